// Round 8
// baseline (1077.607 us; speedup 1.0000x reference)
//
#include <hip/hip_runtime.h>
#include <hip/hip_fp16.h>

#define F_IN 16
#define F_HID 64
#define NPG 8            // nodes per 16-lane group in aggpool
#define NPG16 4          // nodes per 4-lane group in agg16
#define SCAN_CHUNK 1024
#define BN 128           // nodes per CSR-placement bucket (rel fits in 7 bits)

// Combined problem: both graphs concatenated. Node j in [0,2n): graph g=j/n.
// Edge e in [0,2E): graph g=e/E. Segment id = batch[g][..] + g*G.

// ---- CSR build ------------------------------------------------------------

__global__ void degu_kernel(const int* __restrict__ ei1, const int* __restrict__ ei2,
                            int E, int n, unsigned* __restrict__ deg) {
    int t = blockIdx.x * blockDim.x + threadIdx.x;
    int e4 = t * 4;
    if (e4 + 4 <= E) {
        int4 d4 = *(const int4*)(ei1 + E + e4);
        atomicAdd(&deg[d4.x], 1u); atomicAdd(&deg[d4.y], 1u);
        atomicAdd(&deg[d4.z], 1u); atomicAdd(&deg[d4.w], 1u);
    } else if (e4 < E) {
        for (int e = e4; e < E; ++e) atomicAdd(&deg[ei1[E + e]], 1u);
    } else if (e4 - E + 4 <= E) {
        int4 d4 = *(const int4*)(ei2 + (e4 - E) + E);  // ei2 dst
        atomicAdd(&deg[d4.x + n], 1u); atomicAdd(&deg[d4.y + n], 1u);
        atomicAdd(&deg[d4.z + n], 1u); atomicAdd(&deg[d4.w + n], 1u);
    } else if (e4 - E < E) {
        for (int e = e4 - E; e < E; ++e) atomicAdd(&deg[ei2[E + e] + n], 1u);
    }
}

__global__ void scan1_kernel(const unsigned* __restrict__ deg, unsigned* __restrict__ bsum, int n2) {
    __shared__ unsigned s[256];
    int base = blockIdx.x * SCAN_CHUNK;
    unsigned t = 0;
    for (int i = threadIdx.x; i < SCAN_CHUNK; i += 256) {
        int idx = base + i;
        if (idx < n2) t += deg[idx];
    }
    s[threadIdx.x] = t;
    __syncthreads();
    for (int o = 128; o > 0; o >>= 1) {
        if (threadIdx.x < o) s[threadIdx.x] += s[threadIdx.x + o];
        __syncthreads();
    }
    if (threadIdx.x == 0) bsum[blockIdx.x] = s[0];
}

__global__ void scan2_kernel(unsigned* __restrict__ bsum, int nb) {
    if (threadIdx.x == 0 && blockIdx.x == 0) {
        unsigned run = 0;
        for (int i = 0; i < nb; ++i) { unsigned v = bsum[i]; bsum[i] = run; run += v; }
    }
}

// full exclusive scan -> row_start; ALSO computes dinv and xs (fp16, prescaled
// by dinv) since deg is already in hand.
__global__ void scan3_kernel(const unsigned* __restrict__ deg, const unsigned* __restrict__ bsum,
                             const float* __restrict__ x1, const float* __restrict__ x2,
                             int* __restrict__ row_start,
                             float* __restrict__ dinv, __half* __restrict__ xs,
                             int n, int n2, int E2) {
    __shared__ unsigned s[256];
    int tid = threadIdx.x;
    int base = blockIdx.x * SCAN_CHUNK;
    unsigned loc[4];
    unsigned t = 0;
    #pragma unroll
    for (int j = 0; j < 4; ++j) {
        int idx = base + tid * 4 + j;
        loc[j] = (idx < n2) ? deg[idx] : 0u;
        t += loc[j];
    }
    s[tid] = t;
    __syncthreads();
    for (int o = 1; o < 256; o <<= 1) {
        unsigned v = (tid >= o) ? s[tid - o] : 0u;
        __syncthreads();
        s[tid] += v;
        __syncthreads();
    }
    unsigned off = bsum[blockIdx.x] + s[tid] - t;
    #pragma unroll
    for (int j = 0; j < 4; ++j) {
        int idx = base + tid * 4 + j;
        if (idx < n2) {
            row_start[idx] = (int)off;
            float di = rsqrtf((float)loc[j] + 1.0f);
            dinv[idx] = di;
            const float* xr = (idx < n) ? (x1 + (size_t)idx * F_IN)
                                        : (x2 + (size_t)(idx - n) * F_IN);
            const float4* xin = (const float4*)xr;
            union { float4 f4; __half2 h2[4]; } u;
            __half2* xo = (__half2*)(xs + (size_t)idx * F_IN);
            #pragma unroll
            for (int c = 0; c < 2; ++c) {
                float4 v0 = xin[2 * c], v1 = xin[2 * c + 1];
                u.h2[0] = __float22half2_rn(make_float2(v0.x * di, v0.y * di));
                u.h2[1] = __float22half2_rn(make_float2(v0.z * di, v0.w * di));
                u.h2[2] = __float22half2_rn(make_float2(v1.x * di, v1.y * di));
                u.h2[3] = __float22half2_rn(make_float2(v1.z * di, v1.w * di));
                *(float4*)(xo + 4 * c) = u.f4;
            }
        }
        off += loc[j];
    }
    if (blockIdx.x == 0 && tid == 0) row_start[n2] = E2;
}

// bcur[b] = row_start[b*BN]  (bucket append cursors)
__global__ void bcur_init_kernel(const int* __restrict__ row_start,
                                 unsigned* __restrict__ bcur, int NB) {
    int b = blockIdx.x * blockDim.x + threadIdx.x;
    if (b < NB) bcur[b] = (unsigned)row_start[b * BN];
}

// Pass A: append packed (rel<<18 | src) into per-bucket contiguous regions.
// Bucket b of node range [b*BN,(b+1)*BN) owns csr slots [row_start[b*BN], ...).
__device__ inline void bucket_put(int s, int d, unsigned* bcur, unsigned* pairs) {
    int b = d >> 7;            // BN = 128
    unsigned rel = (unsigned)(d & (BN - 1));
    unsigned pos = atomicAdd(&bcur[b], 1u);
    pairs[pos] = (rel << 18) | (unsigned)s;
}

__global__ void bucketA_kernel(const int* __restrict__ ei1, const int* __restrict__ ei2,
                               int E, int n, unsigned* __restrict__ bcur,
                               unsigned* __restrict__ pairs) {
    int t = blockIdx.x * blockDim.x + threadIdx.x;
    int e4 = t * 4;
    if (e4 + 4 <= E) {
        int4 s4 = *(const int4*)(ei1 + e4);
        int4 d4 = *(const int4*)(ei1 + E + e4);
        bucket_put(s4.x, d4.x, bcur, pairs);
        bucket_put(s4.y, d4.y, bcur, pairs);
        bucket_put(s4.z, d4.z, bcur, pairs);
        bucket_put(s4.w, d4.w, bcur, pairs);
    } else if (e4 < E) {
        for (int e = e4; e < E; ++e) bucket_put(ei1[e], ei1[E + e], bcur, pairs);
    } else if (e4 - E + 4 <= E) {
        int eb = e4 - E;
        int4 s4 = *(const int4*)(ei2 + eb);
        int4 d4 = *(const int4*)(ei2 + E + eb);
        bucket_put(s4.x + n, d4.x + n, bcur, pairs);
        bucket_put(s4.y + n, d4.y + n, bcur, pairs);
        bucket_put(s4.z + n, d4.z + n, bcur, pairs);
        bucket_put(s4.w + n, d4.w + n, bcur, pairs);
    } else if (e4 - E < E) {
        for (int e = e4 - E; e < E; ++e)
            bucket_put(ei2[e] + n, ei2[E + e] + n, bcur, pairs);
    }
}

// Pass B: one block per bucket; LDS cursors place each packed edge into the
// bucket's contiguous csr_src slice (reads & writes stay block-local).
__global__ void bucketB_kernel(const unsigned* __restrict__ pairs,
                               const int* __restrict__ row_start,
                               int* __restrict__ csr_src, int n2) {
    __shared__ int cur[BN];
    int b = blockIdx.x;
    int base = b * BN;
    int nn = n2 - base; if (nn > BN) nn = BN;
    for (int i = threadIdx.x; i < nn; i += blockDim.x)
        cur[i] = row_start[base + i];
    __syncthreads();
    int rs_begin = row_start[base];
    int rs_end = row_start[base + nn];
    for (int i = rs_begin + (int)threadIdx.x; i < rs_end; i += blockDim.x) {
        unsigned v = pairs[i];
        int rel = (int)(v >> 18);
        int s = (int)(v & 0x3FFFFu);
        int pos = atomicAdd(&cur[rel], 1);
        csr_src[pos] = s;
    }
}

// ---- gather / dense MLP / pool --------------------------------------------

__device__ inline void acc_row2(float4& a, float2 r) {
    union { float2 f2; __half2 h2[2]; } u; u.f2 = r;
    float2 lo = __half22float2(u.h2[0]), hi = __half22float2(u.h2[1]);
    a.x += lo.x; a.y += lo.y; a.z += hi.x; a.w += hi.y;
}

// Pure 16-dim gather: xagg[j] = dinv[j]*(sum_s xs[s] + xs[j])  (fp16 out).
__global__ void agg16_kernel(const int* __restrict__ csr_src, const int* __restrict__ row_start,
                             const __half* __restrict__ xs, const float* __restrict__ dinv,
                             __half* __restrict__ xagg, int n2) {
    int g4 = threadIdx.x >> 2, lane4 = threadIdx.x & 3;
    int gid = blockIdx.x * 64 + g4;
    int base = gid * NPG16;
    if (base >= n2) return;
    int end_n = base + NPG16;
    if (end_n > n2) end_n = n2;
    for (int node = base; node < end_n; ++node) {
        int start = row_start[node], end = row_start[node + 1];
        float4 acc = make_float4(0.f, 0.f, 0.f, 0.f);
        int e = start;
        for (; e + 4 <= end; e += 4) {
            int i0 = csr_src[e + 0], i1 = csr_src[e + 1];
            int i2 = csr_src[e + 2], i3 = csr_src[e + 3];
            float2 r0 = *(const float2*)(xs + (size_t)i0 * F_IN + lane4 * 4);
            float2 r1 = *(const float2*)(xs + (size_t)i1 * F_IN + lane4 * 4);
            float2 r2 = *(const float2*)(xs + (size_t)i2 * F_IN + lane4 * 4);
            float2 r3 = *(const float2*)(xs + (size_t)i3 * F_IN + lane4 * 4);
            acc_row2(acc, r0); acc_row2(acc, r1); acc_row2(acc, r2); acc_row2(acc, r3);
        }
        for (; e < end; ++e) {
            float2 r0 = *(const float2*)(xs + (size_t)csr_src[e] * F_IN + lane4 * 4);
            acc_row2(acc, r0);
        }
        float2 rs = *(const float2*)(xs + (size_t)node * F_IN + lane4 * 4);
        acc_row2(acc, rs);
        float di = dinv[node];
        union { float2 f2; __half2 h2[2]; } u;
        u.h2[0] = __float22half2_rn(make_float2(acc.x * di, acc.y * di));
        u.h2[1] = __float22half2_rn(make_float2(acc.z * di, acc.w * di));
        *(float2*)(xagg + (size_t)node * F_IN + lane4 * 4) = u.f2;
    }
}

// Dense fused MLP: hw = (relu(xagg @ W1 + b1) * dinv) @ W2, fp16 out.
__global__ __launch_bounds__(256) void mlp_kernel(
        const __half* __restrict__ xagg, const float* __restrict__ dinv,
        const float* __restrict__ W1, const float* __restrict__ b1,
        const float* __restrict__ W2, __half* __restrict__ hw, int n2) {
    __shared__ __align__(16) float w1[F_IN * F_HID];
    __shared__ __align__(16) float w2[F_HID * F_HID];
    __shared__ float b1s[F_HID];
    __shared__ __align__(16) float xl[64][20];
    __shared__ __align__(16) float h1s[64][68];
    int t = threadIdx.x;
    for (int i = t; i < F_IN * F_HID; i += 256) w1[i] = W1[i];
    for (int i = t; i < F_HID * F_HID; i += 256) w2[i] = W2[i];
    if (t < F_HID) b1s[t] = b1[t];

    int base = blockIdx.x * 64;
    int m = t >> 2, jg = t & 3, j0 = jg * 16;
    int node = base + m;
    bool valid = node < n2;

    {
        int k0 = jg * 4;
        if (valid) {
            union { float2 f2; __half2 h2[2]; } u;
            u.f2 = *(const float2*)(xagg + (size_t)node * F_IN + k0);
            float2 lo = __half22float2(u.h2[0]), hi = __half22float2(u.h2[1]);
            *(float4*)&xl[m][k0] = make_float4(lo.x, lo.y, hi.x, hi.y);
        }
    }
    __syncthreads();

    float acc[16];
    #pragma unroll
    for (int jj = 0; jj < 16; ++jj) acc[jj] = 0.0f;
    if (valid) {
        #pragma unroll
        for (int k = 0; k < F_IN; ++k) {
            float xv = xl[m][k];
            const float4* wp = (const float4*)(w1 + k * F_HID + j0);
            #pragma unroll
            for (int q = 0; q < 4; ++q) {
                float4 wv = wp[q];
                acc[4 * q + 0] += xv * wv.x;
                acc[4 * q + 1] += xv * wv.y;
                acc[4 * q + 2] += xv * wv.z;
                acc[4 * q + 3] += xv * wv.w;
            }
        }
        float di = dinv[node];
        #pragma unroll
        for (int jj = 0; jj < 16; ++jj)
            h1s[m][j0 + jj] = fmaxf(acc[jj] + b1s[j0 + jj], 0.0f) * di;
    }
    __syncthreads();

    float o[16];
    #pragma unroll
    for (int jj = 0; jj < 16; ++jj) o[jj] = 0.0f;
    if (valid) {
        #pragma unroll 8
        for (int k = 0; k < F_HID; ++k) {
            float hv = h1s[m][k];
            const float4* wp = (const float4*)(w2 + k * F_HID + j0);
            #pragma unroll
            for (int q = 0; q < 4; ++q) {
                float4 wv = wp[q];
                o[4 * q + 0] += hv * wv.x;
                o[4 * q + 1] += hv * wv.y;
                o[4 * q + 2] += hv * wv.z;
                o[4 * q + 3] += hv * wv.w;
            }
        }
        union { float4 f4; __half2 h2[4]; } p0, p1;
        #pragma unroll
        for (int q = 0; q < 4; ++q) {
            p0.h2[q] = __float22half2_rn(make_float2(o[2 * q], o[2 * q + 1]));
            p1.h2[q] = __float22half2_rn(make_float2(o[8 + 2 * q], o[8 + 2 * q + 1]));
        }
        float4* dst = (float4*)(hw + (size_t)node * F_HID + j0);
        dst[0] = p0.f4;
        dst[1] = p1.f4;
    }
}

// Layer 2 aggregation + relu + segmented global_mean_pool (pure gather).
__global__ void aggpool_kernel(const int* __restrict__ csr_src, const int* __restrict__ row_start,
                               const __half* __restrict__ hw, const float* __restrict__ dinv,
                               const int* __restrict__ batch1, const int* __restrict__ batch2,
                               const float* __restrict__ b2,
                               float* __restrict__ pooled, float* __restrict__ cnt,
                               int n, int G) {
    int n2 = 2 * n;
    int g16 = threadIdx.x >> 4, lane16 = threadIdx.x & 15;
    int gid = blockIdx.x * 16 + g16;
    int base = gid * NPG;
    if (base >= n2) return;
    int end_n = base + NPG;
    if (end_n > n2) end_n = n2;

    const float4 bias = *(const float4*)(b2 + lane16 * 4);
    float4 pacc = make_float4(0.f, 0.f, 0.f, 0.f);
    float count = 0.0f;
    int cur_b = (base < n) ? batch1[base] : (batch2[base - n] + G);

    for (int node = base; node < end_n; ++node) {
        int b = (node < n) ? batch1[node] : (batch2[node - n] + G);
        if (b != cur_b) {
            atomicAdd(&pooled[cur_b * F_HID + lane16 * 4 + 0], pacc.x);
            atomicAdd(&pooled[cur_b * F_HID + lane16 * 4 + 1], pacc.y);
            atomicAdd(&pooled[cur_b * F_HID + lane16 * 4 + 2], pacc.z);
            atomicAdd(&pooled[cur_b * F_HID + lane16 * 4 + 3], pacc.w);
            if (lane16 == 0) atomicAdd(&cnt[cur_b], count);
            pacc = make_float4(0.f, 0.f, 0.f, 0.f); count = 0.0f; cur_b = b;
        }
        int start = row_start[node], end = row_start[node + 1];
        float4 acc = make_float4(0.f, 0.f, 0.f, 0.f);
        int e = start;
        for (; e + 8 <= end; e += 8) {
            int i0 = csr_src[e + 0], i1 = csr_src[e + 1];
            int i2 = csr_src[e + 2], i3 = csr_src[e + 3];
            int i4 = csr_src[e + 4], i5 = csr_src[e + 5];
            int i6 = csr_src[e + 6], i7 = csr_src[e + 7];
            float2 r0 = *(const float2*)(hw + (size_t)i0 * F_HID + lane16 * 4);
            float2 r1 = *(const float2*)(hw + (size_t)i1 * F_HID + lane16 * 4);
            float2 r2 = *(const float2*)(hw + (size_t)i2 * F_HID + lane16 * 4);
            float2 r3 = *(const float2*)(hw + (size_t)i3 * F_HID + lane16 * 4);
            float2 r4 = *(const float2*)(hw + (size_t)i4 * F_HID + lane16 * 4);
            float2 r5 = *(const float2*)(hw + (size_t)i5 * F_HID + lane16 * 4);
            float2 r6 = *(const float2*)(hw + (size_t)i6 * F_HID + lane16 * 4);
            float2 r7 = *(const float2*)(hw + (size_t)i7 * F_HID + lane16 * 4);
            acc_row2(acc, r0); acc_row2(acc, r1); acc_row2(acc, r2); acc_row2(acc, r3);
            acc_row2(acc, r4); acc_row2(acc, r5); acc_row2(acc, r6); acc_row2(acc, r7);
        }
        for (; e < end; ++e) {
            float2 r0 = *(const float2*)(hw + (size_t)csr_src[e] * F_HID + lane16 * 4);
            acc_row2(acc, r0);
        }
        float2 rs = *(const float2*)(hw + (size_t)node * F_HID + lane16 * 4);
        acc_row2(acc, rs);
        float di = dinv[node];
        pacc.x += fmaxf(bias.x + di * acc.x, 0.0f);
        pacc.y += fmaxf(bias.y + di * acc.y, 0.0f);
        pacc.z += fmaxf(bias.z + di * acc.z, 0.0f);
        pacc.w += fmaxf(bias.w + di * acc.w, 0.0f);
        count += 1.0f;
    }
    atomicAdd(&pooled[cur_b * F_HID + lane16 * 4 + 0], pacc.x);
    atomicAdd(&pooled[cur_b * F_HID + lane16 * 4 + 1], pacc.y);
    atomicAdd(&pooled[cur_b * F_HID + lane16 * 4 + 2], pacc.z);
    atomicAdd(&pooled[cur_b * F_HID + lane16 * 4 + 3], pacc.w);
    if (lane16 == 0) atomicAdd(&cnt[cur_b], count);
}

// per graph: combined[128] -> relu(@Wf1 + bf1)[64] -> @Wf2 + bf2 -> out[2]
__global__ void head_kernel(const float* __restrict__ p1, const float* __restrict__ c1,
                            const float* __restrict__ p2, const float* __restrict__ c2,
                            const float* __restrict__ Wf1, const float* __restrict__ bf1,
                            const float* __restrict__ Wf2, const float* __restrict__ bf2,
                            float* __restrict__ out) {
    int g = blockIdx.x;
    int j = threadIdx.x;  // 64 threads, one wave
    __shared__ float comb[128];
    float inv1 = 1.0f / fmaxf(c1[g], 1.0f);
    float inv2 = 1.0f / fmaxf(c2[g], 1.0f);
    comb[j] = p1[g * 64 + j] * inv1;
    comb[64 + j] = p2[g * 64 + j] * inv2;
    __syncthreads();
    float acc = bf1[j];
    #pragma unroll
    for (int k = 0; k < 128; ++k) acc += comb[k] * Wf1[k * 64 + j];
    float h = fmaxf(acc, 0.0f);
    float o0 = h * Wf2[j * 2 + 0];
    float o1 = h * Wf2[j * 2 + 1];
    #pragma unroll
    for (int off = 32; off > 0; off >>= 1) {
        o0 += __shfl_down(o0, off);
        o1 += __shfl_down(o1, off);
    }
    if (j == 0) {
        out[g * 2 + 0] = o0 + bf2[0];
        out[g * 2 + 1] = o1 + bf2[1];
    }
}

extern "C" void kernel_launch(void* const* d_in, const int* in_sizes, int n_in,
                              void* d_out, int out_size, void* d_ws, size_t ws_size,
                              hipStream_t stream) {
    const float* x1     = (const float*)d_in[0];
    const int*   ei1    = (const int*)d_in[1];
    const int*   batch1 = (const int*)d_in[2];
    const float* x2     = (const float*)d_in[3];
    const int*   ei2    = (const int*)d_in[4];
    const int*   batch2 = (const int*)d_in[5];
    const float* W1     = (const float*)d_in[6];
    const float* b1     = (const float*)d_in[7];
    const float* W2     = (const float*)d_in[8];
    const float* b2     = (const float*)d_in[9];
    const float* Wf1    = (const float*)d_in[10];
    const float* bf1    = (const float*)d_in[11];
    const float* Wf2    = (const float*)d_in[12];
    const float* bf2    = (const float*)d_in[13];
    float* out = (float*)d_out;

    const int n = in_sizes[0] / F_IN;   // 100000
    const int E = in_sizes[1] / 2;      // 1600000
    const int G = out_size / 2;         // 256
    const int n2 = 2 * n;
    const int E2 = 2 * E;
    const int nb = (n2 + SCAN_CHUNK - 1) / SCAN_CHUNK;
    const int NB = (n2 + BN - 1) / BN;  // CSR buckets

    char* ws = (char*)d_ws;
    size_t off = 0;
    unsigned* deg    = (unsigned*)(ws + off); off += (size_t)n2 * 4;
    unsigned* bcur   = (unsigned*)(ws + off); off += (size_t)n2 * 4;
    int* row_start   = (int*)(ws + off);      off += (((size_t)n2 + 64) & ~63ull) * 4;
    unsigned* bsum   = (unsigned*)(ws + off); off += (size_t)((nb + 63) & ~63) * 4;
    int* csr_src     = (int*)(ws + off);      off += (size_t)E2 * 4;
    float* dinv      = (float*)(ws + off);    off += (size_t)n2 * 4;
    __half* xs       = (__half*)(ws + off);   off += (size_t)n2 * F_IN * 2;
    __half* xagg     = (__half*)(ws + off);   off += (size_t)n2 * F_IN * 2;
    __half* hwbuf    = (__half*)(ws + off);   off += (size_t)n2 * F_HID * 2;
    float* pooled    = (float*)(ws + off);    off += 2 * (size_t)G * F_HID * 4;
    float* cnt       = (float*)(ws + off);    off += 2 * (size_t)G * 4;

    // pairs (E2 u32 = 12.8 MB) aliases hwbuf (n2*64 fp16 = 25.6 MB): pairs is
    // consumed by bucketB before mlp_kernel writes hw. Stream-ordered -> safe.
    unsigned* pairs = (unsigned*)hwbuf;

    hipMemsetAsync(deg, 0, (size_t)n2 * sizeof(unsigned), stream);
    hipMemsetAsync(pooled, 0, (2 * (size_t)G * F_HID + 2 * (size_t)G) * sizeof(float), stream);

    const int ethreads = (E2 + 3) / 4;
    degu_kernel<<<(ethreads + 255) / 256, 256, 0, stream>>>(ei1, ei2, E, n, deg);

    scan1_kernel<<<nb, 256, 0, stream>>>(deg, bsum, n2);
    scan2_kernel<<<1, 64, 0, stream>>>(bsum, nb);
    scan3_kernel<<<nb, 256, 0, stream>>>(deg, bsum, x1, x2, row_start, dinv, xs, n, n2, E2);

    bcur_init_kernel<<<(NB + 255) / 256, 256, 0, stream>>>(row_start, bcur, NB);
    bucketA_kernel<<<(ethreads + 255) / 256, 256, 0, stream>>>(ei1, ei2, E, n, bcur, pairs);
    bucketB_kernel<<<NB, 256, 0, stream>>>(pairs, row_start, csr_src, n2);

    const int groups16 = (n2 + NPG16 - 1) / NPG16;
    agg16_kernel<<<(groups16 + 63) / 64, 256, 0, stream>>>(csr_src, row_start, xs, dinv, xagg, n2);

    mlp_kernel<<<(n2 + 63) / 64, 256, 0, stream>>>(xagg, dinv, W1, b1, W2, hwbuf, n2);

    const int groups = (n2 + NPG - 1) / NPG;
    aggpool_kernel<<<(groups + 15) / 16, 256, 0, stream>>>(
        csr_src, row_start, hwbuf, dinv, batch1, batch2, b2, pooled, cnt, n, G);

    head_kernel<<<G, 64, 0, stream>>>(pooled, cnt, pooled + (size_t)G * F_HID, cnt + G,
                                      Wf1, bf1, Wf2, bf2, out);
}

// Round 9
// 327.505 us; speedup vs baseline: 3.2903x; 3.2903x over previous
//
#include <hip/hip_runtime.h>
#include <hip/hip_fp16.h>

#define F_IN 16
#define F_HID 64
#define NPG 8            // nodes per 16-lane group in aggpool
#define NPG16 4          // nodes per 4-lane group in agg16
#define SCAN_CHUNK 1024
#define EPB 4096         // edges per radix block
#define BKN 1024         // nodes per coarse bucket (rel = 10 bits)

// Combined problem: both graphs concatenated. Node j in [0,2n): graph g=j/n.
// Edge e in [0,2E): graph g=e/E. Segment id = batch[g][..] + g*G.
// pairs word = (rel10 << 18) | src18   (2n = 200000 < 2^18)

// E and E2 are multiples of 4 (E = 1.6M), so int4 edge loads never straddle.
__device__ inline void load_edge4(const int* __restrict__ ei1, const int* __restrict__ ei2,
                                  int E, int n, int e4, int4& s4, int4& d4) {
    if (e4 < E) {
        s4 = *(const int4*)(ei1 + e4);
        d4 = *(const int4*)(ei1 + E + e4);
    } else {
        int eb = e4 - E;
        s4 = *(const int4*)(ei2 + eb);
        d4 = *(const int4*)(ei2 + E + eb);
        s4.x += n; s4.y += n; s4.z += n; s4.w += n;
        d4.x += n; d4.y += n; d4.z += n; d4.w += n;
    }
}

// ---- radix CSR build (no global atomics) ----------------------------------

// Pass A.1: per-block LDS histogram over coarse buckets -> count[bucket][blk]
__global__ void histA_kernel(const int* __restrict__ ei1, const int* __restrict__ ei2,
                             int E, int n, unsigned* __restrict__ count,
                             int nblkA, int NBK, int E2) {
    __shared__ unsigned hist[256];   // NBK <= 256
    for (int i = threadIdx.x; i < NBK; i += 256) hist[i] = 0;
    __syncthreads();
    int base = blockIdx.x * EPB;
    #pragma unroll
    for (int r = 0; r < EPB / 1024; ++r) {
        int e4 = base + r * 1024 + threadIdx.x * 4;
        if (e4 + 4 <= E2) {
            int4 s4, d4;
            load_edge4(ei1, ei2, E, n, e4, s4, d4);
            atomicAdd(&hist[d4.x >> 10], 1u);
            atomicAdd(&hist[d4.y >> 10], 1u);
            atomicAdd(&hist[d4.z >> 10], 1u);
            atomicAdd(&hist[d4.w >> 10], 1u);
        } else if (e4 < E2) {
            for (int e = e4; e < E2; ++e) {
                int d = (e < E) ? ei1[E + e] : (ei2[e] + n);
                atomicAdd(&hist[d >> 10], 1u);
            }
        }
    }
    __syncthreads();
    for (int i = threadIdx.x; i < NBK; i += 256)
        count[(size_t)i * nblkA + blockIdx.x] = hist[i];
}

__global__ void scan1_kernel(const unsigned* __restrict__ a, unsigned* __restrict__ bsum, int N) {
    __shared__ unsigned s[256];
    int base = blockIdx.x * SCAN_CHUNK;
    unsigned t = 0;
    for (int i = threadIdx.x; i < SCAN_CHUNK; i += 256) {
        int idx = base + i;
        if (idx < N) t += a[idx];
    }
    s[threadIdx.x] = t;
    __syncthreads();
    for (int o = 128; o > 0; o >>= 1) {
        if (threadIdx.x < o) s[threadIdx.x] += s[threadIdx.x + o];
        __syncthreads();
    }
    if (threadIdx.x == 0) bsum[blockIdx.x] = s[0];
}

__global__ void scan2_kernel(unsigned* __restrict__ bsum, int nb) {
    if (threadIdx.x == 0 && blockIdx.x == 0) {
        unsigned run = 0;
        for (int i = 0; i < nb; ++i) { unsigned v = bsum[i]; bsum[i] = run; run += v; }
    }
}

// generic in-place exclusive scan finalize
__global__ void scan3g_kernel(unsigned* __restrict__ a, const unsigned* __restrict__ bsum, int N) {
    __shared__ unsigned s[256];
    int tid = threadIdx.x;
    int base = blockIdx.x * SCAN_CHUNK;
    unsigned loc[4];
    unsigned t = 0;
    #pragma unroll
    for (int j = 0; j < 4; ++j) {
        int idx = base + tid * 4 + j;
        loc[j] = (idx < N) ? a[idx] : 0u;
        t += loc[j];
    }
    s[tid] = t;
    __syncthreads();
    for (int o = 1; o < 256; o <<= 1) {
        unsigned v = (tid >= o) ? s[tid - o] : 0u;
        __syncthreads();
        s[tid] += v;
        __syncthreads();
    }
    unsigned off = bsum[blockIdx.x] + s[tid] - t;
    #pragma unroll
    for (int j = 0; j < 4; ++j) {
        int idx = base + tid * 4 + j;
        if (idx < N) a[idx] = off;
        off += loc[j];
    }
}

// Pass A.2: place edges into pairs via LDS cursors (per-(block,bucket) runs
// are consecutive -> near-line-sized writes, zero global atomics).
__global__ void passA2_kernel(const int* __restrict__ ei1, const int* __restrict__ ei2,
                              int E, int n, const unsigned* __restrict__ cbase,
                              unsigned* __restrict__ pairs, int nblkA, int NBK, int E2) {
    __shared__ unsigned cur[256];
    for (int i = threadIdx.x; i < NBK; i += 256)
        cur[i] = cbase[(size_t)i * nblkA + blockIdx.x];
    __syncthreads();
    int base = blockIdx.x * EPB;
    #pragma unroll
    for (int r = 0; r < EPB / 1024; ++r) {
        int e4 = base + r * 1024 + threadIdx.x * 4;
        if (e4 + 4 <= E2) {
            int4 s4, d4;
            load_edge4(ei1, ei2, E, n, e4, s4, d4);
            unsigned p;
            p = atomicAdd(&cur[d4.x >> 10], 1u);
            pairs[p] = ((unsigned)(d4.x & 1023) << 18) | (unsigned)s4.x;
            p = atomicAdd(&cur[d4.y >> 10], 1u);
            pairs[p] = ((unsigned)(d4.y & 1023) << 18) | (unsigned)s4.y;
            p = atomicAdd(&cur[d4.z >> 10], 1u);
            pairs[p] = ((unsigned)(d4.z & 1023) << 18) | (unsigned)s4.z;
            p = atomicAdd(&cur[d4.w >> 10], 1u);
            pairs[p] = ((unsigned)(d4.w & 1023) << 18) | (unsigned)s4.w;
        } else if (e4 < E2) {
            for (int e = e4; e < E2; ++e) {
                int s = (e < E) ? ei1[e] : (ei2[e - E] + n);
                int d = (e < E) ? ei1[E + e] : (ei2[e] + n);
                unsigned p = atomicAdd(&cur[d >> 10], 1u);
                pairs[p] = ((unsigned)(d & 1023) << 18) | (unsigned)s;
            }
        }
    }
}

// Pass B: one block per bucket. From pairs: per-node degree (LDS), block scan
// -> row_start + dinv + prescaled fp16 xs; then place csr_src via LDS cursors.
// Replaces degu + node-level global scan + old place entirely.
__global__ void bucketB_kernel(const unsigned* __restrict__ pairs,
                               const unsigned* __restrict__ cbase,
                               const float* __restrict__ x1, const float* __restrict__ x2,
                               int* __restrict__ row_start, float* __restrict__ dinv,
                               __half* __restrict__ xs, int* __restrict__ csr_src,
                               int n, int n2, int E2, int nblkA, int NBK) {
    __shared__ unsigned cnt[BKN];
    __shared__ int cur[BKN];
    __shared__ unsigned s[256];
    int b = blockIdx.x;
    int nodebase = b * BKN;
    int nn = n2 - nodebase; if (nn > BKN) nn = BKN;
    unsigned begin = cbase[(size_t)b * nblkA];
    unsigned end = (b + 1 < NBK) ? cbase[(size_t)(b + 1) * nblkA] : (unsigned)E2;
    int t = threadIdx.x;

    for (int i = t; i < BKN; i += 256) cnt[i] = 0;
    __syncthreads();
    for (unsigned i = begin + t; i < end; i += 256)
        atomicAdd(&cnt[pairs[i] >> 18], 1u);
    __syncthreads();

    // block exclusive scan of cnt[0..BKN)
    unsigned loc[4];
    unsigned tot = 0;
    #pragma unroll
    for (int j = 0; j < 4; ++j) { loc[j] = cnt[t * 4 + j]; tot += loc[j]; }
    s[t] = tot;
    __syncthreads();
    for (int o = 1; o < 256; o <<= 1) {
        unsigned v = (t >= o) ? s[t - o] : 0u;
        __syncthreads();
        s[t] += v;
        __syncthreads();
    }
    unsigned off = begin + s[t] - tot;
    #pragma unroll
    for (int j = 0; j < 4; ++j) {
        int i = t * 4 + j;
        if (i < nn) {
            int node = nodebase + i;
            row_start[node] = (int)off;
            cur[i] = (int)off;
            float di = rsqrtf((float)loc[j] + 1.0f);
            dinv[node] = di;
            const float* xr = (node < n) ? (x1 + (size_t)node * F_IN)
                                         : (x2 + (size_t)(node - n) * F_IN);
            const float4* xin = (const float4*)xr;
            union { float4 f4; __half2 h2[4]; } u;
            __half2* xo = (__half2*)(xs + (size_t)node * F_IN);
            #pragma unroll
            for (int c = 0; c < 2; ++c) {
                float4 v0 = xin[2 * c], v1 = xin[2 * c + 1];
                u.h2[0] = __float22half2_rn(make_float2(v0.x * di, v0.y * di));
                u.h2[1] = __float22half2_rn(make_float2(v0.z * di, v0.w * di));
                u.h2[2] = __float22half2_rn(make_float2(v1.x * di, v1.y * di));
                u.h2[3] = __float22half2_rn(make_float2(v1.z * di, v1.w * di));
                *(float4*)(xo + 4 * c) = u.f4;
            }
        }
        off += loc[j];
    }
    __syncthreads();
    for (unsigned i = begin + t; i < end; i += 256) {
        unsigned v = pairs[i];
        int pos = atomicAdd(&cur[v >> 18], 1);
        csr_src[pos] = (int)(v & 0x3FFFFu);
    }
    if (b == 0 && t == 0) row_start[n2] = E2;
}

// ---- gather / dense MLP / pool --------------------------------------------

__device__ inline void acc_row2(float4& a, float2 r) {
    union { float2 f2; __half2 h2[2]; } u; u.f2 = r;
    float2 lo = __half22float2(u.h2[0]), hi = __half22float2(u.h2[1]);
    a.x += lo.x; a.y += lo.y; a.z += hi.x; a.w += hi.y;
}

// Pure 16-dim gather: xagg[j] = dinv[j]*(sum_s xs[s] + xs[j])  (fp16 out).
__global__ void agg16_kernel(const int* __restrict__ csr_src, const int* __restrict__ row_start,
                             const __half* __restrict__ xs, const float* __restrict__ dinv,
                             __half* __restrict__ xagg, int n2) {
    int g4 = threadIdx.x >> 2, lane4 = threadIdx.x & 3;
    int gid = blockIdx.x * 64 + g4;
    int base = gid * NPG16;
    if (base >= n2) return;
    int end_n = base + NPG16;
    if (end_n > n2) end_n = n2;
    for (int node = base; node < end_n; ++node) {
        int start = row_start[node], end = row_start[node + 1];
        float4 acc = make_float4(0.f, 0.f, 0.f, 0.f);
        int e = start;
        for (; e + 4 <= end; e += 4) {
            int i0 = csr_src[e + 0], i1 = csr_src[e + 1];
            int i2 = csr_src[e + 2], i3 = csr_src[e + 3];
            float2 r0 = *(const float2*)(xs + (size_t)i0 * F_IN + lane4 * 4);
            float2 r1 = *(const float2*)(xs + (size_t)i1 * F_IN + lane4 * 4);
            float2 r2 = *(const float2*)(xs + (size_t)i2 * F_IN + lane4 * 4);
            float2 r3 = *(const float2*)(xs + (size_t)i3 * F_IN + lane4 * 4);
            acc_row2(acc, r0); acc_row2(acc, r1); acc_row2(acc, r2); acc_row2(acc, r3);
        }
        for (; e < end; ++e) {
            float2 r0 = *(const float2*)(xs + (size_t)csr_src[e] * F_IN + lane4 * 4);
            acc_row2(acc, r0);
        }
        float2 rs = *(const float2*)(xs + (size_t)node * F_IN + lane4 * 4);
        acc_row2(acc, rs);
        float di = dinv[node];
        union { float2 f2; __half2 h2[2]; } u;
        u.h2[0] = __float22half2_rn(make_float2(acc.x * di, acc.y * di));
        u.h2[1] = __float22half2_rn(make_float2(acc.z * di, acc.w * di));
        *(float2*)(xagg + (size_t)node * F_IN + lane4 * 4) = u.f2;
    }
}

// Dense fused MLP: hw = (relu(xagg @ W1 + b1) * dinv) @ W2, fp16 out.
__global__ __launch_bounds__(256) void mlp_kernel(
        const __half* __restrict__ xagg, const float* __restrict__ dinv,
        const float* __restrict__ W1, const float* __restrict__ b1,
        const float* __restrict__ W2, __half* __restrict__ hw, int n2) {
    __shared__ __align__(16) float w1[F_IN * F_HID];
    __shared__ __align__(16) float w2[F_HID * F_HID];
    __shared__ float b1s[F_HID];
    __shared__ __align__(16) float xl[64][20];
    __shared__ __align__(16) float h1s[64][68];
    int t = threadIdx.x;
    for (int i = t; i < F_IN * F_HID; i += 256) w1[i] = W1[i];
    for (int i = t; i < F_HID * F_HID; i += 256) w2[i] = W2[i];
    if (t < F_HID) b1s[t] = b1[t];

    int base = blockIdx.x * 64;
    int m = t >> 2, jg = t & 3, j0 = jg * 16;
    int node = base + m;
    bool valid = node < n2;

    {
        int k0 = jg * 4;
        if (valid) {
            union { float2 f2; __half2 h2[2]; } u;
            u.f2 = *(const float2*)(xagg + (size_t)node * F_IN + k0);
            float2 lo = __half22float2(u.h2[0]), hi = __half22float2(u.h2[1]);
            *(float4*)&xl[m][k0] = make_float4(lo.x, lo.y, hi.x, hi.y);
        }
    }
    __syncthreads();

    float acc[16];
    #pragma unroll
    for (int jj = 0; jj < 16; ++jj) acc[jj] = 0.0f;
    if (valid) {
        #pragma unroll
        for (int k = 0; k < F_IN; ++k) {
            float xv = xl[m][k];
            const float4* wp = (const float4*)(w1 + k * F_HID + j0);
            #pragma unroll
            for (int q = 0; q < 4; ++q) {
                float4 wv = wp[q];
                acc[4 * q + 0] += xv * wv.x;
                acc[4 * q + 1] += xv * wv.y;
                acc[4 * q + 2] += xv * wv.z;
                acc[4 * q + 3] += xv * wv.w;
            }
        }
        float di = dinv[node];
        #pragma unroll
        for (int jj = 0; jj < 16; ++jj)
            h1s[m][j0 + jj] = fmaxf(acc[jj] + b1s[j0 + jj], 0.0f) * di;
    }
    __syncthreads();

    float o[16];
    #pragma unroll
    for (int jj = 0; jj < 16; ++jj) o[jj] = 0.0f;
    if (valid) {
        #pragma unroll 8
        for (int k = 0; k < F_HID; ++k) {
            float hv = h1s[m][k];
            const float4* wp = (const float4*)(w2 + k * F_HID + j0);
            #pragma unroll
            for (int q = 0; q < 4; ++q) {
                float4 wv = wp[q];
                o[4 * q + 0] += hv * wv.x;
                o[4 * q + 1] += hv * wv.y;
                o[4 * q + 2] += hv * wv.z;
                o[4 * q + 3] += hv * wv.w;
            }
        }
        union { float4 f4; __half2 h2[4]; } p0, p1;
        #pragma unroll
        for (int q = 0; q < 4; ++q) {
            p0.h2[q] = __float22half2_rn(make_float2(o[2 * q], o[2 * q + 1]));
            p1.h2[q] = __float22half2_rn(make_float2(o[8 + 2 * q], o[8 + 2 * q + 1]));
        }
        float4* dst = (float4*)(hw + (size_t)node * F_HID + j0);
        dst[0] = p0.f4;
        dst[1] = p1.f4;
    }
}

// Layer 2 aggregation + relu + segmented global_mean_pool (pure gather).
__global__ void aggpool_kernel(const int* __restrict__ csr_src, const int* __restrict__ row_start,
                               const __half* __restrict__ hw, const float* __restrict__ dinv,
                               const int* __restrict__ batch1, const int* __restrict__ batch2,
                               const float* __restrict__ b2,
                               float* __restrict__ pooled, float* __restrict__ cnt,
                               int n, int G) {
    int n2 = 2 * n;
    int g16 = threadIdx.x >> 4, lane16 = threadIdx.x & 15;
    int gid = blockIdx.x * 16 + g16;
    int base = gid * NPG;
    if (base >= n2) return;
    int end_n = base + NPG;
    if (end_n > n2) end_n = n2;

    const float4 bias = *(const float4*)(b2 + lane16 * 4);
    float4 pacc = make_float4(0.f, 0.f, 0.f, 0.f);
    float count = 0.0f;
    int cur_b = (base < n) ? batch1[base] : (batch2[base - n] + G);

    for (int node = base; node < end_n; ++node) {
        int b = (node < n) ? batch1[node] : (batch2[node - n] + G);
        if (b != cur_b) {
            atomicAdd(&pooled[cur_b * F_HID + lane16 * 4 + 0], pacc.x);
            atomicAdd(&pooled[cur_b * F_HID + lane16 * 4 + 1], pacc.y);
            atomicAdd(&pooled[cur_b * F_HID + lane16 * 4 + 2], pacc.z);
            atomicAdd(&pooled[cur_b * F_HID + lane16 * 4 + 3], pacc.w);
            if (lane16 == 0) atomicAdd(&cnt[cur_b], count);
            pacc = make_float4(0.f, 0.f, 0.f, 0.f); count = 0.0f; cur_b = b;
        }
        int start = row_start[node], end = row_start[node + 1];
        float4 acc = make_float4(0.f, 0.f, 0.f, 0.f);
        int e = start;
        for (; e + 8 <= end; e += 8) {
            int i0 = csr_src[e + 0], i1 = csr_src[e + 1];
            int i2 = csr_src[e + 2], i3 = csr_src[e + 3];
            int i4 = csr_src[e + 4], i5 = csr_src[e + 5];
            int i6 = csr_src[e + 6], i7 = csr_src[e + 7];
            float2 r0 = *(const float2*)(hw + (size_t)i0 * F_HID + lane16 * 4);
            float2 r1 = *(const float2*)(hw + (size_t)i1 * F_HID + lane16 * 4);
            float2 r2 = *(const float2*)(hw + (size_t)i2 * F_HID + lane16 * 4);
            float2 r3 = *(const float2*)(hw + (size_t)i3 * F_HID + lane16 * 4);
            float2 r4 = *(const float2*)(hw + (size_t)i4 * F_HID + lane16 * 4);
            float2 r5 = *(const float2*)(hw + (size_t)i5 * F_HID + lane16 * 4);
            float2 r6 = *(const float2*)(hw + (size_t)i6 * F_HID + lane16 * 4);
            float2 r7 = *(const float2*)(hw + (size_t)i7 * F_HID + lane16 * 4);
            acc_row2(acc, r0); acc_row2(acc, r1); acc_row2(acc, r2); acc_row2(acc, r3);
            acc_row2(acc, r4); acc_row2(acc, r5); acc_row2(acc, r6); acc_row2(acc, r7);
        }
        for (; e < end; ++e) {
            float2 r0 = *(const float2*)(hw + (size_t)csr_src[e] * F_HID + lane16 * 4);
            acc_row2(acc, r0);
        }
        float2 rs = *(const float2*)(hw + (size_t)node * F_HID + lane16 * 4);
        acc_row2(acc, rs);
        float di = dinv[node];
        pacc.x += fmaxf(bias.x + di * acc.x, 0.0f);
        pacc.y += fmaxf(bias.y + di * acc.y, 0.0f);
        pacc.z += fmaxf(bias.z + di * acc.z, 0.0f);
        pacc.w += fmaxf(bias.w + di * acc.w, 0.0f);
        count += 1.0f;
    }
    atomicAdd(&pooled[cur_b * F_HID + lane16 * 4 + 0], pacc.x);
    atomicAdd(&pooled[cur_b * F_HID + lane16 * 4 + 1], pacc.y);
    atomicAdd(&pooled[cur_b * F_HID + lane16 * 4 + 2], pacc.z);
    atomicAdd(&pooled[cur_b * F_HID + lane16 * 4 + 3], pacc.w);
    if (lane16 == 0) atomicAdd(&cnt[cur_b], count);
}

// per graph: combined[128] -> relu(@Wf1 + bf1)[64] -> @Wf2 + bf2 -> out[2]
__global__ void head_kernel(const float* __restrict__ p1, const float* __restrict__ c1,
                            const float* __restrict__ p2, const float* __restrict__ c2,
                            const float* __restrict__ Wf1, const float* __restrict__ bf1,
                            const float* __restrict__ Wf2, const float* __restrict__ bf2,
                            float* __restrict__ out) {
    int g = blockIdx.x;
    int j = threadIdx.x;  // 64 threads, one wave
    __shared__ float comb[128];
    float inv1 = 1.0f / fmaxf(c1[g], 1.0f);
    float inv2 = 1.0f / fmaxf(c2[g], 1.0f);
    comb[j] = p1[g * 64 + j] * inv1;
    comb[64 + j] = p2[g * 64 + j] * inv2;
    __syncthreads();
    float acc = bf1[j];
    #pragma unroll
    for (int k = 0; k < 128; ++k) acc += comb[k] * Wf1[k * 64 + j];
    float h = fmaxf(acc, 0.0f);
    float o0 = h * Wf2[j * 2 + 0];
    float o1 = h * Wf2[j * 2 + 1];
    #pragma unroll
    for (int off = 32; off > 0; off >>= 1) {
        o0 += __shfl_down(o0, off);
        o1 += __shfl_down(o1, off);
    }
    if (j == 0) {
        out[g * 2 + 0] = o0 + bf2[0];
        out[g * 2 + 1] = o1 + bf2[1];
    }
}

extern "C" void kernel_launch(void* const* d_in, const int* in_sizes, int n_in,
                              void* d_out, int out_size, void* d_ws, size_t ws_size,
                              hipStream_t stream) {
    const float* x1     = (const float*)d_in[0];
    const int*   ei1    = (const int*)d_in[1];
    const int*   batch1 = (const int*)d_in[2];
    const float* x2     = (const float*)d_in[3];
    const int*   ei2    = (const int*)d_in[4];
    const int*   batch2 = (const int*)d_in[5];
    const float* W1     = (const float*)d_in[6];
    const float* b1     = (const float*)d_in[7];
    const float* W2     = (const float*)d_in[8];
    const float* b2     = (const float*)d_in[9];
    const float* Wf1    = (const float*)d_in[10];
    const float* bf1    = (const float*)d_in[11];
    const float* Wf2    = (const float*)d_in[12];
    const float* bf2    = (const float*)d_in[13];
    float* out = (float*)d_out;

    const int n = in_sizes[0] / F_IN;   // 100000
    const int E = in_sizes[1] / 2;      // 1600000
    const int G = out_size / 2;         // 256
    const int n2 = 2 * n;
    const int E2 = 2 * E;
    const int NBK = (n2 + BKN - 1) / BKN;         // coarse buckets (196)
    const int nblkA = (E2 + EPB - 1) / EPB;       // radix blocks (782)
    const int N_A = NBK * nblkA;                  // count-matrix entries
    const int nbA = (N_A + SCAN_CHUNK - 1) / SCAN_CHUNK;

    char* ws = (char*)d_ws;
    size_t off = 0;
    unsigned* count  = (unsigned*)(ws + off); off += (((size_t)N_A + 63) & ~63ull) * 4;
    unsigned* bsumA  = (unsigned*)(ws + off); off += (size_t)((nbA + 63) & ~63) * 4;
    int* row_start   = (int*)(ws + off);      off += (((size_t)n2 + 64) & ~63ull) * 4;
    int* csr_src     = (int*)(ws + off);      off += (size_t)E2 * 4;
    float* dinv      = (float*)(ws + off);    off += (size_t)n2 * 4;
    __half* xs       = (__half*)(ws + off);   off += (size_t)n2 * F_IN * 2;
    __half* xagg     = (__half*)(ws + off);   off += (size_t)n2 * F_IN * 2;
    __half* hwbuf    = (__half*)(ws + off);   off += (size_t)n2 * F_HID * 2;
    float* pooled    = (float*)(ws + off);    off += 2 * (size_t)G * F_HID * 4;
    float* cnt       = (float*)(ws + off);    off += 2 * (size_t)G * 4;

    // pairs (E2 u32 = 12.8 MB) aliases hwbuf (25.6 MB): consumed by bucketB
    // before mlp_kernel writes hw. Stream-ordered -> safe.
    unsigned* pairs = (unsigned*)hwbuf;

    hipMemsetAsync(pooled, 0, (2 * (size_t)G * F_HID + 2 * (size_t)G) * sizeof(float), stream);

    histA_kernel<<<nblkA, 256, 0, stream>>>(ei1, ei2, E, n, count, nblkA, NBK, E2);
    scan1_kernel<<<nbA, 256, 0, stream>>>(count, bsumA, N_A);
    scan2_kernel<<<1, 64, 0, stream>>>(bsumA, nbA);
    scan3g_kernel<<<nbA, 256, 0, stream>>>(count, bsumA, N_A);
    passA2_kernel<<<nblkA, 256, 0, stream>>>(ei1, ei2, E, n, count, pairs, nblkA, NBK, E2);
    bucketB_kernel<<<NBK, 256, 0, stream>>>(pairs, count, x1, x2, row_start, dinv, xs,
                                            csr_src, n, n2, E2, nblkA, NBK);

    const int groups16 = (n2 + NPG16 - 1) / NPG16;
    agg16_kernel<<<(groups16 + 63) / 64, 256, 0, stream>>>(csr_src, row_start, xs, dinv, xagg, n2);

    mlp_kernel<<<(n2 + 63) / 64, 256, 0, stream>>>(xagg, dinv, W1, b1, W2, hwbuf, n2);

    const int groups = (n2 + NPG - 1) / NPG;
    aggpool_kernel<<<(groups + 15) / 16, 256, 0, stream>>>(
        csr_src, row_start, hwbuf, dinv, batch1, batch2, b2, pooled, cnt, n, G);

    head_kernel<<<G, 64, 0, stream>>>(pooled, cnt, pooled + (size_t)G * F_HID, cnt + G,
                                      Wf1, bf1, Wf2, bf2, out);
}